// Round 5
// baseline (294.069 us; speedup 1.0000x reference)
//
#include <hip/hip_runtime.h>

// B=2, SQ=SKV=2048, D=1024, H=16, HD=64.
// Established: device inputs fp32, device OUTPUT fp32 (ref output dtype; the
// "bf16" in the test label is hard-coded text). Threshold = 2% relative.
// r2/r3/r4 identical absmax 0.2793 > max|ref|=0.1875 == bf16-written-to-fp32-buffer
// signature; math itself was correct.
#define DIM   1024
#define NHEAD 16
#define HDIM  64
#define BATCH 2
#define SEQ   2048
#define MTOT  4096   // B*SQ

typedef unsigned short u16;
typedef unsigned int   u32;
typedef __attribute__((ext_vector_type(8))) short bf16x8;   // 8 bf16 = 4 VGPRs
typedef __attribute__((ext_vector_type(4))) short u16x4;    // 8B LDS write
typedef __attribute__((ext_vector_type(4))) float f32x4;

__device__ __forceinline__ u16 f32_to_bf16(float f) {
  union { float f; u32 u; } v; v.f = f;
  u32 r = v.u + 0x7fffu + ((v.u >> 16) & 1u);   // RNE
  return (u16)(r >> 16);
}

// ---------------------------------------------------------------------------
// GEMM: C[4096,1024] = (X @ W^T + bias) * scale.  W,bias fp32 [N,K] row-major.
// X fp32 (QKV proj) or bf16 (O proj). Output bf16 (workspace) or fp32 (final).
// 128x128 tile, BK=64, 4 waves (2x2), wave tile 64x64 = 4x4 frags 16x16x32.
// Register staging -> ds_write, LDS row stride 72 halfwords (pad, no swizzle).
// ---------------------------------------------------------------------------
template<bool XBF16, bool OUTF32>
__device__ __forceinline__ void gemm128_body(
    const void* __restrict__ Xv, const float* __restrict__ Wf,
    const float* __restrict__ bias, void* __restrict__ Cv, float scale)
{
  __shared__ __align__(16) u16 ldsA[128 * 72];
  __shared__ __align__(16) u16 ldsB[128 * 72];
  const int tid  = threadIdx.x;
  const int lane = tid & 63;
  const int wid  = tid >> 6;
  const int wr   = wid >> 1, wc = wid & 1;
  const int m0 = blockIdx.y * 128;
  const int n0 = blockIdx.x * 128;

  f32x4 acc[4][4];
#pragma unroll
  for (int mf = 0; mf < 4; ++mf)
#pragma unroll
    for (int nf = 0; nf < 4; ++nf)
#pragma unroll
      for (int r = 0; r < 4; ++r) acc[mf][nf][r] = 0.f;

  for (int kt = 0; kt < DIM; kt += 64) {
    __syncthreads();
    if (XBF16) {
      const u16* X = (const u16*)Xv;
#pragma unroll
      for (int it = 0; it < 4; ++it) {
        int c = it * 256 + tid;                // [0,1024): 8 chunks x 128 rows
        int row = c >> 3, cc = c & 7;
        bf16x8 x = *(const bf16x8*)&X[(size_t)(m0 + row) * DIM + kt + cc * 8];
        *(bf16x8*)&ldsA[row * 72 + cc * 8] = x;
      }
    } else {
      const float* X = (const float*)Xv;
#pragma unroll
      for (int it = 0; it < 8; ++it) {
        int f = it * 256 + tid;                // [0,2048): 16 float4 x 128 rows
        int row = f >> 4, c4 = f & 15;
        float4 x = *(const float4*)&X[(size_t)(m0 + row) * DIM + kt + c4 * 4];
        u16x4 o;
        o[0] = (short)f32_to_bf16(x.x); o[1] = (short)f32_to_bf16(x.y);
        o[2] = (short)f32_to_bf16(x.z); o[3] = (short)f32_to_bf16(x.w);
        *(u16x4*)&ldsA[row * 72 + c4 * 4] = o;
      }
    }
#pragma unroll
    for (int it = 0; it < 8; ++it) {
      int f = it * 256 + tid;
      int row = f >> 4, c4 = f & 15;
      float4 x = *(const float4*)&Wf[(size_t)(n0 + row) * DIM + kt + c4 * 4];
      u16x4 o;
      o[0] = (short)f32_to_bf16(x.x); o[1] = (short)f32_to_bf16(x.y);
      o[2] = (short)f32_to_bf16(x.z); o[3] = (short)f32_to_bf16(x.w);
      *(u16x4*)&ldsB[row * 72 + c4 * 4] = o;
    }
    __syncthreads();

#pragma unroll
    for (int ks = 0; ks < 2; ++ks) {
      bf16x8 af[4], bfr[4];
#pragma unroll
      for (int mf = 0; mf < 4; ++mf) {
        int row = wr * 64 + mf * 16 + (lane & 15);
        af[mf] = *(const bf16x8*)&ldsA[row * 72 + (ks * 4 + (lane >> 4)) * 8];
      }
#pragma unroll
      for (int nf = 0; nf < 4; ++nf) {
        int row = wc * 64 + nf * 16 + (lane & 15);
        bfr[nf] = *(const bf16x8*)&ldsB[row * 72 + (ks * 4 + (lane >> 4)) * 8];
      }
#pragma unroll
      for (int mf = 0; mf < 4; ++mf)
#pragma unroll
        for (int nf = 0; nf < 4; ++nf)
          acc[mf][nf] = __builtin_amdgcn_mfma_f32_16x16x32_bf16(
              af[mf], bfr[nf], acc[mf][nf], 0, 0, 0);
    }
  }
  // epilogue: C/D layout col=lane&15, row=(lane>>4)*4+r
#pragma unroll
  for (int nf = 0; nf < 4; ++nf) {
    int col = n0 + wc * 64 + nf * 16 + (lane & 15);
    float bv = bias[col];
#pragma unroll
    for (int mf = 0; mf < 4; ++mf) {
      int rbase = m0 + wr * 64 + mf * 16 + ((lane >> 4) << 2);
#pragma unroll
      for (int r = 0; r < 4; ++r) {
        float v = (acc[mf][nf][r] + bv) * scale;
        if (OUTF32) ((float*)Cv)[(size_t)(rbase + r) * DIM + col] = v;
        else        ((u16*)Cv)[(size_t)(rbase + r) * DIM + col] = f32_to_bf16(v);
      }
    }
  }
}

__global__ __launch_bounds__(256, 2) void gemm_qkv_kernel(
    const float* __restrict__ q, const float* __restrict__ k, const float* __restrict__ v,
    const float* __restrict__ wq, const float* __restrict__ wk, const float* __restrict__ wv,
    const float* __restrict__ bq, const float* __restrict__ bk, const float* __restrict__ bv,
    u16* __restrict__ oq, u16* __restrict__ ok, u16* __restrict__ ov)
{
  const int z = blockIdx.z;
  const float* X = (z == 0) ? q  : (z == 1) ? k  : v;
  const float* W = (z == 0) ? wq : (z == 1) ? wk : wv;
  const float* B = (z == 0) ? bq : (z == 1) ? bk : bv;
  u16*         C = (z == 0) ? oq : (z == 1) ? ok : ov;
  gemm128_body<false, false>(X, W, B, C, (z == 0) ? 0.125f : 1.0f);  // 1/sqrt(64) into Q
}

__global__ __launch_bounds__(256, 2) void gemm_o_kernel(
    const u16* __restrict__ x, const float* __restrict__ w,
    const float* __restrict__ b, float* __restrict__ c)
{
  gemm128_body<true, true>(x, w, b, c, 1.0f);
}

// ---------------------------------------------------------------------------
// Flash attention. grid = (SQ/128, B*H), 4 waves, wave owns 32 q-rows.
// ---------------------------------------------------------------------------
__global__ __launch_bounds__(256, 2) void attn_kernel(
    const u16* __restrict__ Qm, const u16* __restrict__ Km,
    const u16* __restrict__ Vm, u16* __restrict__ Cm)
{
  __shared__ __align__(16) u16 Kl[64 * 72];        // [kv][72]
  __shared__ __align__(16) u16 Vt[64][72];         // [d][kv] padded
  __shared__ __align__(16) u16 Pl[4][32 * 72];     // per-wave P [32 q][72]

  const int tid = threadIdx.x, lane = tid & 63, wid = tid >> 6;
  const int qt = blockIdx.x;
  const int b  = blockIdx.y >> 4, h = blockIdx.y & 15;
  const size_t hb = (size_t)h * HDIM;
  const u16* Qh = Qm + ((size_t)b * SEQ + qt * 128) * DIM + hb;
  const u16* Kh = Km + (size_t)b * SEQ * DIM + hb;
  const u16* Vh = Vm + (size_t)b * SEQ * DIM + hb;

  bf16x8 qf[2][2];
#pragma unroll
  for (int mf = 0; mf < 2; ++mf)
#pragma unroll
    for (int ks = 0; ks < 2; ++ks)
      qf[mf][ks] = *(const bf16x8*)(Qh +
          (size_t)(wid * 32 + mf * 16 + (lane & 15)) * DIM + ks * 32 + ((lane >> 4) << 3));

  float mrow[2][4], ell[2][4];
  f32x4 oacc[2][4];
#pragma unroll
  for (int mf = 0; mf < 2; ++mf)
#pragma unroll
    for (int r = 0; r < 4; ++r) { mrow[mf][r] = -1e30f; ell[mf][r] = 0.f; }
#pragma unroll
  for (int mf = 0; mf < 2; ++mf)
#pragma unroll
    for (int nf = 0; nf < 4; ++nf)
#pragma unroll
      for (int r = 0; r < 4; ++r) oacc[mf][nf][r] = 0.f;

  const int srow = tid >> 3, scs = tid & 7;
  u16* pw = &Pl[wid][0];

  for (int kv0 = 0; kv0 < SEQ; kv0 += 64) {
    __syncthreads();
#pragma unroll
    for (int it = 0; it < 2; ++it) {
      int c = it * 256 + tid;                  // [0,512): 8 chunks x 64 rows
      int row = c >> 3, cc = c & 7;
      bf16x8 kx = *(const bf16x8*)&Kh[(size_t)(kv0 + row) * DIM + cc * 8];
      *(bf16x8*)&Kl[row * 72 + cc * 8] = kx;
    }
#pragma unroll
    for (int pass = 0; pass < 2; ++pass) {
      int row = pass * 32 + srow;
      bf16x8 vv = *(const bf16x8*)(Vh + (size_t)(kv0 + row) * DIM + scs * 8);
#pragma unroll
      for (int j = 0; j < 8; ++j)
        Vt[scs * 8 + j][row] = (u16)((const short*)&vv)[j];
    }
    __syncthreads();

    f32x4 sacc[2][4];
#pragma unroll
    for (int mf = 0; mf < 2; ++mf)
#pragma unroll
      for (int nf = 0; nf < 4; ++nf)
#pragma unroll
        for (int r = 0; r < 4; ++r) sacc[mf][nf][r] = 0.f;
#pragma unroll
    for (int ks = 0; ks < 2; ++ks) {
      bf16x8 kf[4];
#pragma unroll
      for (int nf = 0; nf < 4; ++nf) {
        int row = nf * 16 + (lane & 15);
        kf[nf] = *(const bf16x8*)&Kl[row * 72 + (ks * 4 + (lane >> 4)) * 8];
      }
#pragma unroll
      for (int mf = 0; mf < 2; ++mf)
#pragma unroll
        for (int nf = 0; nf < 4; ++nf)
          sacc[mf][nf] = __builtin_amdgcn_mfma_f32_16x16x32_bf16(
              qf[mf][ks], kf[nf], sacc[mf][nf], 0, 0, 0);
    }

#pragma unroll
    for (int mf = 0; mf < 2; ++mf) {
#pragma unroll
      for (int r = 0; r < 4; ++r) {
        float mx = fmaxf(fmaxf(sacc[mf][0][r], sacc[mf][1][r]),
                         fmaxf(sacc[mf][2][r], sacc[mf][3][r]));
#pragma unroll
        for (int d = 1; d < 16; d <<= 1) mx = fmaxf(mx, __shfl_xor(mx, d));
        float mn = fmaxf(mrow[mf][r], mx);
        float al = __expf(mrow[mf][r] - mn);
        mrow[mf][r] = mn;
        float rs = 0.f;
#pragma unroll
        for (int nf = 0; nf < 4; ++nf) {
          float p = __expf(sacc[mf][nf][r] - mn);
          sacc[mf][nf][r] = p;
          rs += p;
        }
#pragma unroll
        for (int d = 1; d < 16; d <<= 1) rs += __shfl_xor(rs, d);
        ell[mf][r] = ell[mf][r] * al + rs;
#pragma unroll
        for (int nf = 0; nf < 4; ++nf) oacc[mf][nf][r] *= al;
      }
    }

#pragma unroll
    for (int mf = 0; mf < 2; ++mf)
#pragma unroll
      for (int nf = 0; nf < 4; ++nf) {
        int col = nf * 16 + (lane & 15);
#pragma unroll
        for (int r = 0; r < 4; ++r) {
          int qrow = mf * 16 + ((lane >> 4) << 2) + r;
          pw[qrow * 72 + col] = f32_to_bf16(sacc[mf][nf][r]);
        }
      }
#pragma unroll
    for (int ks = 0; ks < 2; ++ks) {
      bf16x8 pf[2], vf[4];
#pragma unroll
      for (int mf = 0; mf < 2; ++mf)
        pf[mf] = *(const bf16x8*)&pw[(mf * 16 + (lane & 15)) * 72 + ks * 32 + ((lane >> 4) << 3)];
#pragma unroll
      for (int nf = 0; nf < 4; ++nf)
        vf[nf] = *(const bf16x8*)&Vt[nf * 16 + (lane & 15)][ks * 32 + ((lane >> 4) << 3)];
#pragma unroll
      for (int mf = 0; mf < 2; ++mf)
#pragma unroll
        for (int nf = 0; nf < 4; ++nf)
          oacc[mf][nf] = __builtin_amdgcn_mfma_f32_16x16x32_bf16(
              pf[mf], vf[nf], oacc[mf][nf], 0, 0, 0);
    }
  }

  const int q0 = qt * 128 + wid * 32;
#pragma unroll
  for (int mf = 0; mf < 2; ++mf)
#pragma unroll
    for (int nf = 0; nf < 4; ++nf) {
      int dcol = nf * 16 + (lane & 15);
#pragma unroll
      for (int r = 0; r < 4; ++r) {
        int q = q0 + mf * 16 + ((lane >> 4) << 2) + r;
        float v = oacc[mf][nf][r] / ell[mf][r];
        Cm[((size_t)b * SEQ + q) * DIM + hb + dcol] = f32_to_bf16(v);
      }
    }
}

// ---------------------------------------------------------------------------
extern "C" void kernel_launch(void* const* d_in, const int* in_sizes, int n_in,
                              void* d_out, int out_size, void* d_ws, size_t ws_size,
                              hipStream_t stream)
{
  const float* query = (const float*)d_in[0];
  const float* key   = (const float*)d_in[1];
  const float* value = (const float*)d_in[2];
  const float* Wq = (const float*)d_in[3];  const float* bq = (const float*)d_in[4];
  const float* Wk = (const float*)d_in[5];  const float* bk = (const float*)d_in[6];
  const float* Wv = (const float*)d_in[7];  const float* bv = (const float*)d_in[8];
  const float* Wo = (const float*)d_in[9];  const float* bo = (const float*)d_in[10];
  float* out = (float*)d_out;               // fp32 output (reference dtype)

  const size_t NQKV = (size_t)MTOT * DIM;   // bf16 workspace buffers
  u16* Qb = (u16*)d_ws;
  u16* Kb = Qb + NQKV;
  u16* Vb = Kb + NQKV;
  u16* Cb = Vb + NQKV;

  dim3 blk(256);
  gemm_qkv_kernel<<<dim3(DIM / 128, MTOT / 128, 3), blk, 0, stream>>>(
      query, key, value, Wq, Wk, Wv, bq, bk, bv, Qb, Kb, Vb);
  attn_kernel<<<dim3(SEQ / 128, BATCH * NHEAD), blk, 0, stream>>>(Qb, Kb, Vb, Cb);
  gemm_o_kernel<<<dim3(DIM / 128, MTOT / 128, 1), blk, 0, stream>>>(Cb, Wo, bo, out);
}

// Round 7
// 235.885 us; speedup vs baseline: 1.2467x; 1.2467x over previous
//
#include <hip/hip_runtime.h>

// B=2, SQ=SKV=2048, D=1024, H=16, HD=64. Inputs fp32, output fp32.
// r5 passed (294us): attn 161us (LDS conflicts 2e7, Vt-transpose staging = 8-16-way),
// GEMMs 133us (fp32 staging, no gload_lds).
// r6/r7: (1) V^T computed by the V-projection GEMM -> attn reads V^T & K B-frags
// directly from global (contiguous 16B), P-only LDS, NO barriers in attn loop;
// (2) one fp32->bf16 convert pass + r2's proven gload_lds+swizzle GEMM everywhere;
// (3) exp2-domain softmax (scale folded into Q projection).
// r7 fix: __exp2f doesn't exist in device code -> __builtin_amdgcn_exp2f.
#define DIM   1024
#define NHEAD 16
#define HDIM  64
#define BATCH 2
#define SEQ   2048
#define MTOT  4096   // B*SQ

typedef unsigned short u16;
typedef unsigned int   u32;
typedef __attribute__((ext_vector_type(8))) short bf16x8;   // 8 bf16 = 4 VGPRs
typedef __attribute__((ext_vector_type(4))) float f32x4;
typedef __attribute__((ext_vector_type(4))) u32   u32x4;

#define QSCALE 0.18033688011112042f   // 0.125 * log2(e): exp2-domain softmax
#define EXP2F(x) __builtin_amdgcn_exp2f(x)

__device__ __forceinline__ void gload_lds16(const void* g, void* l) {
  __builtin_amdgcn_global_load_lds((const __attribute__((address_space(1))) void*)g,
                                   (__attribute__((address_space(3))) void*)l, 16, 0, 0);
}

__device__ __forceinline__ u16 f32_to_bf16(float f) {
  union { float f; u32 u; } v; v.f = f;
  u32 r = v.u + 0x7fffu + ((v.u >> 16) & 1u);   // RNE
  return (u16)(r >> 16);
}

// ---------------------------------------------------------------------------
// One-shot fp32 -> bf16 conversion of all 7 tensors (3 inputs + 4 weights).
// ---------------------------------------------------------------------------
struct CvtArgs {
  const float* s[7];
  u16*         d[7];
  int          n8[7];   // element_count / 8
};

__global__ __launch_bounds__(256) void cvt_all(CvtArgs a) {
  const int z = blockIdx.z;
  const float* s = a.s[z];
  u16* d = a.d[z];
  const int n8 = a.n8[z];
  const int stride = gridDim.x * blockDim.x;
  for (int i = blockIdx.x * blockDim.x + threadIdx.x; i < n8; i += stride) {
    float4 x = ((const float4*)s)[2 * i], y = ((const float4*)s)[2 * i + 1];
    u16 o[8] = { f32_to_bf16(x.x), f32_to_bf16(x.y), f32_to_bf16(x.z), f32_to_bf16(x.w),
                 f32_to_bf16(y.x), f32_to_bf16(y.y), f32_to_bf16(y.z), f32_to_bf16(y.w) };
    *(u32x4*)&d[(size_t)i * 8] = *(const u32x4*)o;
  }
}

// ---------------------------------------------------------------------------
// bf16 GEMM (r2-proven structure): C[M,N] = X[M,K=1024] @ W[N,K=1024]^T + bias.
// 128x128 tile, BK=64, 4 waves (2x2). gload_lds staging with XOR swizzle on the
// GLOBAL source + swizzled ds_read (G21 both-sides).
// BIAS_ROW: bias indexed by output row (for the transposed V GEMM).
// ---------------------------------------------------------------------------
template<bool OUTF32, bool BIAS_ROW>
__device__ __forceinline__ void gemm_body(
    const u16* __restrict__ X, const u16* __restrict__ W,
    const float* __restrict__ bias, void* __restrict__ Cv, int ldc, float scale)
{
  __shared__ __align__(16) u16 ldsA[128 * 64];
  __shared__ __align__(16) u16 ldsB[128 * 64];
  const int tid  = threadIdx.x;
  const int lane = tid & 63;
  const int wid  = tid >> 6;
  const int wr   = wid >> 1, wc = wid & 1;
  const int m0 = blockIdx.y * 128;
  const int n0 = blockIdx.x * 128;
  const int srow = tid >> 3;
  const int scs  = tid & 7;

  f32x4 acc[4][4];
#pragma unroll
  for (int mf = 0; mf < 4; ++mf)
#pragma unroll
    for (int nf = 0; nf < 4; ++nf)
#pragma unroll
      for (int r = 0; r < 4; ++r) acc[mf][nf][r] = 0.f;

  for (int kt = 0; kt < DIM; kt += 64) {
    __syncthreads();
#pragma unroll
    for (int call = 0; call < 4; ++call) {
      int row = call * 32 + srow;
      int lc  = scs ^ (row & 7);               // inverse-swizzled global chunk
      gload_lds16(X + (size_t)(m0 + row) * DIM + kt + lc * 8,
                  &ldsA[(row * 8 + scs) * 8]);
      gload_lds16(W + (size_t)(n0 + row) * DIM + kt + lc * 8,
                  &ldsB[(row * 8 + scs) * 8]);
    }
    __syncthreads();
#pragma unroll
    for (int ks = 0; ks < 2; ++ks) {
      bf16x8 af[4], bfr[4];
#pragma unroll
      for (int mf = 0; mf < 4; ++mf) {
        int row = wr * 64 + mf * 16 + (lane & 15);
        int ch  = (ks * 4 + (lane >> 4)) ^ (row & 7);
        af[mf] = *(const bf16x8*)&ldsA[row * 64 + ch * 8];
      }
#pragma unroll
      for (int nf = 0; nf < 4; ++nf) {
        int row = wc * 64 + nf * 16 + (lane & 15);
        int ch  = (ks * 4 + (lane >> 4)) ^ (row & 7);
        bfr[nf] = *(const bf16x8*)&ldsB[row * 64 + ch * 8];
      }
#pragma unroll
      for (int mf = 0; mf < 4; ++mf)
#pragma unroll
        for (int nf = 0; nf < 4; ++nf)
          acc[mf][nf] = __builtin_amdgcn_mfma_f32_16x16x32_bf16(
              af[mf], bfr[nf], acc[mf][nf], 0, 0, 0);
    }
  }
  // epilogue: C/D layout col=lane&15, row=(lane>>4)*4+r
#pragma unroll
  for (int nf = 0; nf < 4; ++nf) {
    int col = n0 + wc * 64 + nf * 16 + (lane & 15);
    float bcol = BIAS_ROW ? 0.f : bias[col];
#pragma unroll
    for (int mf = 0; mf < 4; ++mf) {
      int rbase = m0 + wr * 64 + mf * 16 + ((lane >> 4) << 2);
#pragma unroll
      for (int r = 0; r < 4; ++r) {
        float bv = BIAS_ROW ? bias[rbase + r] : bcol;
        float v = (acc[mf][nf][r] + bv) * scale;
        if (OUTF32) ((float*)Cv)[(size_t)(rbase + r) * ldc + col] = v;
        else        ((u16*)Cv)[(size_t)(rbase + r) * ldc + col] = f32_to_bf16(v);
      }
    }
  }
}

// z=0: Q = query@Wq^T (scaled by QSCALE), z=1: K = key@Wk^T
__global__ __launch_bounds__(256, 2) void gemm_qk_kernel(
    const u16* __restrict__ q, const u16* __restrict__ k,
    const u16* __restrict__ wq, const u16* __restrict__ wk,
    const float* __restrict__ bq, const float* __restrict__ bk,
    u16* __restrict__ oq, u16* __restrict__ ok)
{
  if (blockIdx.z == 0)
    gemm_body<false, false>(q, wq, bq, oq, DIM, QSCALE);
  else
    gemm_body<false, false>(k, wk, bk, ok, DIM, 1.0f);
}

// V^T[ch][tok] = Wv @ value^T : X=Wv (M=1024), W=value (N=4096), bias per-row.
__global__ __launch_bounds__(256, 2) void gemm_vt_kernel(
    const u16* __restrict__ wv, const u16* __restrict__ value,
    const float* __restrict__ bv, u16* __restrict__ vt)
{
  gemm_body<false, true>(wv, value, bv, vt, MTOT, 1.0f);
}

__global__ __launch_bounds__(256, 2) void gemm_o_kernel(
    const u16* __restrict__ x, const u16* __restrict__ w,
    const float* __restrict__ b, float* __restrict__ c)
{
  gemm_body<true, false>(x, w, b, c, DIM, 1.0f);
}

// ---------------------------------------------------------------------------
// Flash attention, barrier-free. grid = (SQ/128, B*H), 4 waves x 32 q-rows.
// Q pre-scaled by 0.125*log2e -> exp2-domain softmax.
// K and V^T B-fragments read directly from global (contiguous 16B per lane).
// Only P round-trips through per-wave LDS (stride 76 u16).
// ---------------------------------------------------------------------------
#define PSTR 76

__global__ __launch_bounds__(256, 2) void attn_kernel(
    const u16* __restrict__ Qm, const u16* __restrict__ Km,
    const u16* __restrict__ Vt, u16* __restrict__ Cm)
{
  __shared__ __align__(16) u16 Pl[4][32 * PSTR];

  const int tid = threadIdx.x, lane = tid & 63, wid = tid >> 6;
  const int qt = blockIdx.x;
  const int b  = blockIdx.y >> 4, h = blockIdx.y & 15;
  const size_t hb = (size_t)h * HDIM;
  const u16* Qh = Qm + ((size_t)b * SEQ + qt * 128) * DIM + hb;
  const u16* Kh = Km + (size_t)b * SEQ * DIM + hb;
  // V^T: [1024 ch][4096 tok]; this head+batch: row ch = h*64+d, col tok = b*2048+kv
  const u16* Vh = Vt + (size_t)(h * HDIM) * MTOT + (size_t)b * SEQ;

  bf16x8 qf[2][2];
#pragma unroll
  for (int mf = 0; mf < 2; ++mf)
#pragma unroll
    for (int ks = 0; ks < 2; ++ks)
      qf[mf][ks] = *(const bf16x8*)(Qh +
          (size_t)(wid * 32 + mf * 16 + (lane & 15)) * DIM + ks * 32 + ((lane >> 4) << 3));

  float mrow[2][4], ell[2][4];
  f32x4 oacc[2][4];
#pragma unroll
  for (int mf = 0; mf < 2; ++mf)
#pragma unroll
    for (int r = 0; r < 4; ++r) { mrow[mf][r] = -1e30f; ell[mf][r] = 0.f; }
#pragma unroll
  for (int mf = 0; mf < 2; ++mf)
#pragma unroll
    for (int nf = 0; nf < 4; ++nf)
#pragma unroll
      for (int r = 0; r < 4; ++r) oacc[mf][nf][r] = 0.f;

  u16* pw = &Pl[wid][0];

  for (int kv0 = 0; kv0 < SEQ; kv0 += 64) {
    // --- K B-frags direct from global: B[k=d][n=kv] = K[kv][d], 16B/lane ---
    bf16x8 kf[2][4];
#pragma unroll
    for (int ks = 0; ks < 2; ++ks)
#pragma unroll
      for (int nf = 0; nf < 4; ++nf)
        kf[ks][nf] = *(const bf16x8*)(Kh +
            (size_t)(kv0 + nf * 16 + (lane & 15)) * DIM + ks * 32 + ((lane >> 4) << 3));

    f32x4 sacc[2][4];
#pragma unroll
    for (int mf = 0; mf < 2; ++mf)
#pragma unroll
      for (int nf = 0; nf < 4; ++nf)
#pragma unroll
        for (int r = 0; r < 4; ++r) sacc[mf][nf][r] = 0.f;
#pragma unroll
    for (int ks = 0; ks < 2; ++ks)
#pragma unroll
      for (int mf = 0; mf < 2; ++mf)
#pragma unroll
        for (int nf = 0; nf < 4; ++nf)
          sacc[mf][nf] = __builtin_amdgcn_mfma_f32_16x16x32_bf16(
              qf[mf][ks], kf[ks][nf], sacc[mf][nf], 0, 0, 0);

    // --- issue V^T loads early; latency hides under softmax ---
    bf16x8 vf[2][4];
#pragma unroll
    for (int ks = 0; ks < 2; ++ks)
#pragma unroll
      for (int nf = 0; nf < 4; ++nf)
        vf[ks][nf] = *(const bf16x8*)(Vh +
            (size_t)(nf * 16 + (lane & 15)) * MTOT + kv0 + ks * 32 + ((lane >> 4) << 3));

    // --- online softmax (exp2 domain; scores pre-scaled via Q) ---
#pragma unroll
    for (int mf = 0; mf < 2; ++mf) {
#pragma unroll
      for (int r = 0; r < 4; ++r) {
        float mx = fmaxf(fmaxf(sacc[mf][0][r], sacc[mf][1][r]),
                         fmaxf(sacc[mf][2][r], sacc[mf][3][r]));
#pragma unroll
        for (int d = 1; d < 16; d <<= 1) mx = fmaxf(mx, __shfl_xor(mx, d));
        float mn = fmaxf(mrow[mf][r], mx);
        float al = EXP2F(mrow[mf][r] - mn);
        mrow[mf][r] = mn;
        float rs = 0.f;
#pragma unroll
        for (int nf = 0; nf < 4; ++nf) {
          float p = EXP2F(sacc[mf][nf][r] - mn);
          sacc[mf][nf][r] = p;
          rs += p;
        }
#pragma unroll
        for (int d = 1; d < 16; d <<= 1) rs += __shfl_xor(rs, d);
        ell[mf][r] = ell[mf][r] * al + rs;
#pragma unroll
        for (int nf = 0; nf < 4; ++nf) oacc[mf][nf][r] *= al;
      }
    }

    // --- P -> per-wave LDS (C-layout scatter, stride 76), read as A-frags ---
#pragma unroll
    for (int mf = 0; mf < 2; ++mf)
#pragma unroll
      for (int nf = 0; nf < 4; ++nf) {
        int col = nf * 16 + (lane & 15);
#pragma unroll
        for (int r = 0; r < 4; ++r) {
          int qrow = mf * 16 + ((lane >> 4) << 2) + r;
          pw[qrow * PSTR + col] = f32_to_bf16(sacc[mf][nf][r]);
        }
      }
#pragma unroll
    for (int ks = 0; ks < 2; ++ks) {
      bf16x8 pf[2];
#pragma unroll
      for (int mf = 0; mf < 2; ++mf)
        pf[mf] = *(const bf16x8*)&pw[(mf * 16 + (lane & 15)) * PSTR + ks * 32 + ((lane >> 4) << 3)];
#pragma unroll
      for (int mf = 0; mf < 2; ++mf)
#pragma unroll
        for (int nf = 0; nf < 4; ++nf)
          oacc[mf][nf] = __builtin_amdgcn_mfma_f32_16x16x32_bf16(
              pf[mf], vf[ks][nf], oacc[mf][nf], 0, 0, 0);
    }
  }

  const int q0 = qt * 128 + wid * 32;
#pragma unroll
  for (int mf = 0; mf < 2; ++mf)
#pragma unroll
    for (int nf = 0; nf < 4; ++nf) {
      int dcol = nf * 16 + (lane & 15);
#pragma unroll
      for (int r = 0; r < 4; ++r) {
        int q = q0 + mf * 16 + ((lane >> 4) << 2) + r;
        float v = oacc[mf][nf][r] / ell[mf][r];
        Cm[((size_t)b * SEQ + q) * DIM + hb + dcol] = f32_to_bf16(v);
      }
    }
}

// ---------------------------------------------------------------------------
extern "C" void kernel_launch(void* const* d_in, const int* in_sizes, int n_in,
                              void* d_out, int out_size, void* d_ws, size_t ws_size,
                              hipStream_t stream)
{
  const float* query = (const float*)d_in[0];
  const float* key   = (const float*)d_in[1];
  const float* value = (const float*)d_in[2];
  const float* Wq = (const float*)d_in[3];  const float* bq = (const float*)d_in[4];
  const float* Wk = (const float*)d_in[5];  const float* bk = (const float*)d_in[6];
  const float* Wv = (const float*)d_in[7];  const float* bv = (const float*)d_in[8];
  const float* Wo = (const float*)d_in[9];  const float* bo = (const float*)d_in[10];
  float* out = (float*)d_out;

  const size_t NQKV = (size_t)MTOT * DIM;   // 4,194,304
  const size_t NW   = (size_t)DIM * DIM;    // 1,048,576
  u16* base = (u16*)d_ws;
  u16* Qb  = base;                 // [4096,1024] bf16 (pre-scaled by QSCALE)
  u16* Kb  = Qb + NQKV;            // [4096,1024]
  u16* Vtb = Kb + NQKV;            // [1024,4096]  V^T
  u16* Cb  = Vtb + NQKV;           // [4096,1024]  attn output
  u16* qc  = Cb + NQKV;            // converted inputs/weights
  u16* kc  = qc + NQKV;
  u16* vc  = kc + NQKV;
  u16* wqc = vc + NQKV;
  u16* wkc = wqc + NW;
  u16* wvc = wkc + NW;
  u16* woc = wvc + NW;
  // total: 4*8.4 + 3*8.4 + 4*2.1 MB ~= 67 MB

  CvtArgs ca;
  ca.s[0] = query; ca.s[1] = key; ca.s[2] = value;
  ca.s[3] = Wq; ca.s[4] = Wk; ca.s[5] = Wv; ca.s[6] = Wo;
  ca.d[0] = qc; ca.d[1] = kc; ca.d[2] = vc;
  ca.d[3] = wqc; ca.d[4] = wkc; ca.d[5] = wvc; ca.d[6] = woc;
  for (int i = 0; i < 3; ++i) ca.n8[i] = (int)(NQKV / 8);
  for (int i = 3; i < 7; ++i) ca.n8[i] = (int)(NW / 8);
  cvt_all<<<dim3(256, 1, 7), 256, 0, stream>>>(ca);

  dim3 blk(256);
  gemm_qk_kernel<<<dim3(DIM / 128, MTOT / 128, 2), blk, 0, stream>>>(
      qc, kc, wqc, wkc, bq, bk, Qb, Kb);
  gemm_vt_kernel<<<dim3(MTOT / 128, DIM / 128, 1), blk, 0, stream>>>(
      wvc, vc, bv, Vtb);
  attn_kernel<<<dim3(SEQ / 128, BATCH * NHEAD), blk, 0, stream>>>(Qb, Kb, Vtb, Cb);
  gemm_o_kernel<<<dim3(DIM / 128, MTOT / 128, 1), blk, 0, stream>>>(Cb, woc, bo, out);
}